// Round 7
// baseline (165.086 us; speedup 1.0000x reference)
//
#include <hip/hip_runtime.h>
#include <hip/hip_bf16.h>

// Nat2D neighborhood attention, MI355X gfx950.
// Device ABI: f32 inputs, f32 output. bf16 MFMA for GEMMs, bf16 qkv intermediate.
// Pipeline: [cast3 x,Wqkv,Wproj -> bf16] -> [gemm_lds QKV -> bf16 qkv] ->
//           [natten_direct: no K/V staging, L1/L2-served, 8x8 tile x head] ->
//           [gemm_lds proj -> f32 out]

typedef __attribute__((ext_vector_type(4))) float f32x4;
typedef __attribute__((ext_vector_type(8))) short bf16x8;
typedef __attribute__((ext_vector_type(4))) short s16x4;

#define HEADS 8
#define HEAD_DIM 64
#define DIM 512
#define KW 7
#define HH 80
#define WW 80
#define NPIX (HH * WW)

__device__ inline unsigned short f2bf(float f) {
    union { __hip_bfloat16 b; unsigned short u; } cvt;
    cvt.b = __float2bfloat16(f);
    return cvt.u;
}
__device__ inline float bf2f(short s) {
    union { float f; unsigned u; } c;
    c.u = ((unsigned)(unsigned short)s) << 16;
    return c.f;
}

__device__ inline void storeC(float* p, float v) { *p = v; }
__device__ inline void storeC(__hip_bfloat16* p, float v) { *p = __float2bfloat16(v); }

// async global->LDS, 16B per lane. LDS dest must be linear in lane order.
__device__ inline void g2l16(const void* g, void* l) {
    __builtin_amdgcn_global_load_lds(
        (const __attribute__((address_space(1))) unsigned int*)g,
        (__attribute__((address_space(3))) unsigned int*)l,
        16, 0, 0);
}

// Fused f32 -> bf16 cast for three arrays (x, qkv_w, proj_w).
__global__ __launch_bounds__(256) void cast3_f32_bf16(
    const float* __restrict__ a, short* __restrict__ oa, int na4,
    const float* __restrict__ b, short* __restrict__ ob, int nb4,
    const float* __restrict__ c, short* __restrict__ oc, int nc4)
{
    int i = blockIdx.x * 256 + threadIdx.x;
    const float* src; short* dst; int idx;
    if (i < na4) { src = a; dst = oa; idx = i; }
    else if (i < na4 + nb4) { src = b; dst = ob; idx = i - na4; }
    else if (i < na4 + nb4 + nc4) { src = c; dst = oc; idx = i - na4 - nb4; }
    else return;
    f32x4 v = reinterpret_cast<const f32x4*>(src)[idx];
    s16x4 r;
#pragma unroll
    for (int j = 0; j < 4; ++j) r[j] = (short)f2bf(v[j]);
    reinterpret_cast<s16x4*>(dst)[idx] = r;
}

// C[m,n] = sum_k A[m,k] * W[n,k] + bias[n]   (A @ W^T + b)
// 128x128 tile, BK=64, 4 waves in 2x2 quadrants, dbuf LDS via
// global_load_lds(16B), XOR-swizzle on SOURCE + ds_read (rule #21).
template <typename CT>
__global__ __launch_bounds__(256) void gemm_lds(
    const __hip_bfloat16* __restrict__ A,
    const __hip_bfloat16* __restrict__ W,
    const float* __restrict__ bias,
    CT* __restrict__ C,
    int M, int N, int K)
{
    __shared__ short lds[2][2][128][64];

    const int lane = threadIdx.x & 63;
    const int wv = threadIdx.x >> 6;
    const int wr = wv >> 1;
    const int wc = wv & 1;
    const int r0 = blockIdx.y * 128;
    const int c0 = blockIdx.x * 128;
    const int rf = lane & 15;
    const int kg = lane >> 4;

    const int NT = K >> 6;

    auto stage = [&](const __hip_bfloat16* src, int rowbase, int kb, short* dst) {
#pragma unroll
        for (int q = 0; q < 4; ++q) {
            const int L = wv * 256 + q * 64 + lane;
            const int r = L >> 3;
            const int cs = (L & 7) ^ (r & 7);
            g2l16(src + (size_t)(rowbase + r) * K + kb + cs * 8, dst + (size_t)L * 8);
        }
    };
    auto frag = [&](const short* base, int row, int ch) -> bf16x8 {
        return *reinterpret_cast<const bf16x8*>(base + row * 64 + ((ch ^ (row & 7)) << 3));
    };

    f32x4 acc[4][4] = {};

    stage(A, r0, 0, &lds[0][0][0][0]);
    stage(W, c0, 0, &lds[0][1][0][0]);
    __syncthreads();

    int cur = 0;
    for (int t = 0; t < NT; ++t) {
        if (t + 1 < NT) {
            stage(A, r0, (t + 1) * 64, &lds[cur ^ 1][0][0][0]);
            stage(W, c0, (t + 1) * 64, &lds[cur ^ 1][1][0][0]);
        }
        const short* la = &lds[cur][0][0][0];
        const short* lb = &lds[cur][1][0][0];
#pragma unroll
        for (int ks = 0; ks < 2; ++ks) {
            bf16x8 af[4], bfr[4];
#pragma unroll
            for (int i = 0; i < 4; ++i)
                af[i] = frag(la, wr * 64 + i * 16 + rf, ks * 4 + kg);
#pragma unroll
            for (int j = 0; j < 4; ++j)
                bfr[j] = frag(lb, wc * 64 + j * 16 + rf, ks * 4 + kg);
#pragma unroll
            for (int i = 0; i < 4; ++i)
#pragma unroll
                for (int j = 0; j < 4; ++j)
                    acc[i][j] = __builtin_amdgcn_mfma_f32_16x16x32_bf16(af[i], bfr[j], acc[i][j], 0, 0, 0);
        }
        __syncthreads();
        cur ^= 1;
    }

    // C/D layout: col = lane&15, row = (lane>>4)*4 + reg  [m89-verified]
#pragma unroll
    for (int j = 0; j < 4; ++j) {
        const int col = c0 + wc * 64 + j * 16 + rf;
        const float bcol = bias[col];
#pragma unroll
        for (int i = 0; i < 4; ++i) {
#pragma unroll
            for (int r = 0; r < 4; ++r) {
                const int row = r0 + wr * 64 + i * 16 + kg * 4 + r;
                storeC(C + (size_t)row * N + col, acc[i][j][r] + bcol);
            }
        }
    }
}

// Direct natten: block = (8x8 pixel tile) x (one head), 256 threads = 4 waves.
// NO K/V LDS staging (per-block unique K/V ~50KB is L1/L2-served; staging
// cost occupancy: 70KB LDS -> 14% occ). LDS = per-pixel weights + rpb only.
// Thread (p, g): pixel p (0..63), dim-quarter g (0..3) -> dims g*16..g*16+15.
__global__ __launch_bounds__(256) void natten_direct(
    const __hip_bfloat16* __restrict__ qkv,
    const float* __restrict__ rpb,
    __hip_bfloat16* __restrict__ aout)
{
    __shared__ float sW[64][52];   // 13312 B
    __shared__ float sB[169];      // rpb[h] slice

    const int tid = threadIdx.x;
    const int h = blockIdx.y;
    const int ti = blockIdx.x / 10;
    const int tj = blockIdx.x - ti * 10;

    if (tid < 169) sB[tid] = rpb[h * 169 + tid];
    __syncthreads();

    const int lane = tid & 63;
    const int wv = tid >> 6;
    const int p = wv * 16 + (lane >> 2);   // tile-local pixel 0..63
    const int g = lane & 3;                // dim quarter
    const int pi = ti * 8 + (p >> 3);
    const int pj = tj * 8 + (p & 7);
    int si = pi - 3; si = si < 0 ? 0 : (si > (HH - KW) ? (HH - KW) : si);
    int sj = pj - 3; sj = sj < 0 ? 0 : (sj > (WW - KW) ? (WW - KW) : sj);
    const int oh = si - pi + 6;
    const int ow = sj - pj + 6;

    const __hip_bfloat16* qkv_hd = qkv + h * 64 + g * 16;

    // q fragment (16 dims) with 1/8 scale folded in
    float qf[16];
    {
        const __hip_bfloat16* qsrc = qkv_hd + (size_t)(pi * WW + pj) * 1536;
        bf16x8 q0 = *reinterpret_cast<const bf16x8*>(qsrc);
        bf16x8 q1 = *reinterpret_cast<const bf16x8*>(qsrc + 8);
#pragma unroll
        for (int j = 0; j < 8; ++j) {
            qf[j] = 0.125f * bf2f(q0[j]);
            qf[8 + j] = 0.125f * bf2f(q1[j]);
        }
    }

    // Phase 1: 49 logits per pixel, K from global (L1/L2)
#pragma unroll
    for (int a = 0; a < KW; ++a) {
        const int rbase = (si + a) * WW + sj;
        const float* brow = &sB[(oh + a) * 13 + ow];
#pragma unroll
        for (int c = 0; c < KW; ++c) {
            const __hip_bfloat16* kp = qkv_hd + (size_t)(rbase + c) * 1536 + 512;
            bf16x8 k0 = *reinterpret_cast<const bf16x8*>(kp);
            bf16x8 k1 = *reinterpret_cast<const bf16x8*>(kp + 8);
            float d = 0.f;
#pragma unroll
            for (int j = 0; j < 8; ++j) d += qf[j] * bf2f(k0[j]);
#pragma unroll
            for (int j = 0; j < 8; ++j) d += qf[8 + j] * bf2f(k1[j]);
            d += __shfl_xor(d, 1, 64);
            d += __shfl_xor(d, 2, 64);
            if (g == 0) sW[p][a * KW + c] = d + brow[c];
        }
    }
    // sW[p] accessed only by this wave's own lanes -> no barrier needed.

    // Phase 2: softmax over 49, 4-way parallel across g-lanes
    float m = -1e30f;
    for (int i = g; i < 49; i += 4) m = fmaxf(m, sW[p][i]);
    m = fmaxf(m, __shfl_xor(m, 1, 64));
    m = fmaxf(m, __shfl_xor(m, 2, 64));
    float s = 0.f;
    for (int i = g; i < 49; i += 4) {
        const float e = __expf(sW[p][i] - m);
        s += e;
        sW[p][i] = e;
    }
    s += __shfl_xor(s, 1, 64);
    s += __shfl_xor(s, 2, 64);
    const float rs = 1.0f / s;

    // Phase 3: o[d] = (1/s) * sum_nb e_nb * v[nb][d], V from global
    float o[16];
#pragma unroll
    for (int j = 0; j < 16; ++j) o[j] = 0.f;
#pragma unroll
    for (int a = 0; a < KW; ++a) {
        const int rbase = (si + a) * WW + sj;
#pragma unroll
        for (int c = 0; c < KW; ++c) {
            const float w = sW[p][a * KW + c];
            const __hip_bfloat16* vp = qkv_hd + (size_t)(rbase + c) * 1536 + 1024;
            bf16x8 v0 = *reinterpret_cast<const bf16x8*>(vp);
            bf16x8 v1 = *reinterpret_cast<const bf16x8*>(vp + 8);
#pragma unroll
            for (int j = 0; j < 8; ++j) o[j] += w * bf2f(v0[j]);
#pragma unroll
            for (int j = 0; j < 8; ++j) o[8 + j] += w * bf2f(v1[j]);
        }
    }

    bf16x8 r0v, r1v;
#pragma unroll
    for (int j = 0; j < 8; ++j) {
        r0v[j] = (short)f2bf(o[j] * rs);
        r1v[j] = (short)f2bf(o[8 + j] * rs);
    }
    __hip_bfloat16* dst = aout + ((size_t)(pi * WW + pj) * 512 + h * 64 + g * 16);
    *reinterpret_cast<bf16x8*>(dst) = r0v;
    *reinterpret_cast<bf16x8*>(dst + 8) = r1v;
}

extern "C" void kernel_launch(void* const* d_in, const int* in_sizes, int n_in,
                              void* d_out, int out_size, void* d_ws, size_t ws_size,
                              hipStream_t stream) {
    const float* x      = (const float*)d_in[0];
    const float* qkv_w  = (const float*)d_in[1];
    const float* qkv_b  = (const float*)d_in[2];
    const float* rpb    = (const float*)d_in[3];
    const float* proj_w = (const float*)d_in[4];
    const float* proj_b = (const float*)d_in[5];
    float* out = (float*)d_out;

    // ws layout (all bf16): xb | wqkv | wproj | qkv | aout  = 34.9 MB total
    char* wsb = (char*)d_ws;
    __hip_bfloat16* xb    = (__hip_bfloat16*)wsb;                 // 6,553,600 B
    __hip_bfloat16* wqkv  = (__hip_bfloat16*)(wsb + 6553600);     // 1,572,864 B
    __hip_bfloat16* wproj = (__hip_bfloat16*)(wsb + 8126464);     //   524,288 B
    __hip_bfloat16* qkv   = (__hip_bfloat16*)(wsb + 8650752);     // 19,660,800 B
    __hip_bfloat16* aout  = (__hip_bfloat16*)(wsb + 28311552);    // 6,553,600 B

    dim3 blk(256);
    cast3_f32_bf16<<<dim3((819200 + 196608 + 65536 + 255) / 256), blk, 0, stream>>>(
        x, (short*)xb, 819200, qkv_w, (short*)wqkv, 196608, proj_w, (short*)wproj, 65536);

    gemm_lds<__hip_bfloat16><<<dim3((3 * DIM) / 128, NPIX / 128), blk, 0, stream>>>(
        xb, wqkv, qkv_b, qkv, NPIX, 3 * DIM, DIM);

    natten_direct<<<dim3(100, 8), blk, 0, stream>>>(qkv, rpb, aout);

    gemm_lds<float><<<dim3(DIM / 128, NPIX / 128), blk, 0, stream>>>(
        aout, wproj, proj_b, out, NPIX, DIM, DIM);
}

// Round 8
// 143.812 us; speedup vs baseline: 1.1479x; 1.1479x over previous
//
#include <hip/hip_runtime.h>
#include <hip/hip_bf16.h>

// Nat2D neighborhood attention, MI355X gfx950.
// Device ABI: f32 inputs, f32 output. bf16 MFMA for GEMMs, bf16 qkv intermediate.
// Pipeline: [cast3 -> bf16] -> [gemm_lds QKV -> bf16 qkv] ->
//           [natten_kv: K/V time-share one LDS buffer, register softmax] ->
//           [gemm_lds proj -> f32 out]

typedef __attribute__((ext_vector_type(4))) float f32x4;
typedef __attribute__((ext_vector_type(8))) short bf16x8;
typedef __attribute__((ext_vector_type(4))) short s16x4;

#define HEADS 8
#define HEAD_DIM 64
#define DIM 512
#define KW 7
#define HH 80
#define WW 80
#define NPIX (HH * WW)

__device__ inline unsigned short f2bf(float f) {
    union { __hip_bfloat16 b; unsigned short u; } cvt;
    cvt.b = __float2bfloat16(f);
    return cvt.u;
}
__device__ inline float bf2f(short s) {
    union { float f; unsigned u; } c;
    c.u = ((unsigned)(unsigned short)s) << 16;
    return c.f;
}

__device__ inline void storeC(float* p, float v) { *p = v; }
__device__ inline void storeC(__hip_bfloat16* p, float v) { *p = __float2bfloat16(v); }

// async global->LDS, 16B per lane. LDS dest must be linear in lane order.
__device__ inline void g2l16(const void* g, void* l) {
    __builtin_amdgcn_global_load_lds(
        (const __attribute__((address_space(1))) unsigned int*)g,
        (__attribute__((address_space(3))) unsigned int*)l,
        16, 0, 0);
}

// Fused f32 -> bf16 cast for three arrays (x, qkv_w, proj_w).
__global__ __launch_bounds__(256) void cast3_f32_bf16(
    const float* __restrict__ a, short* __restrict__ oa, int na4,
    const float* __restrict__ b, short* __restrict__ ob, int nb4,
    const float* __restrict__ c, short* __restrict__ oc, int nc4)
{
    int i = blockIdx.x * 256 + threadIdx.x;
    const float* src; short* dst; int idx;
    if (i < na4) { src = a; dst = oa; idx = i; }
    else if (i < na4 + nb4) { src = b; dst = ob; idx = i - na4; }
    else if (i < na4 + nb4 + nc4) { src = c; dst = oc; idx = i - na4 - nb4; }
    else return;
    f32x4 v = reinterpret_cast<const f32x4*>(src)[idx];
    s16x4 r;
#pragma unroll
    for (int j = 0; j < 4; ++j) r[j] = (short)f2bf(v[j]);
    reinterpret_cast<s16x4*>(dst)[idx] = r;
}

// C[m,n] = sum_k A[m,k] * W[n,k] + bias[n]   (A @ W^T + b)
// 128x128 tile, BK=64, 4 waves in 2x2 quadrants, dbuf LDS via
// global_load_lds(16B), XOR-swizzle on SOURCE + ds_read (rule #21).
template <typename CT>
__global__ __launch_bounds__(256) void gemm_lds(
    const __hip_bfloat16* __restrict__ A,
    const __hip_bfloat16* __restrict__ W,
    const float* __restrict__ bias,
    CT* __restrict__ C,
    int M, int N, int K)
{
    __shared__ short lds[2][2][128][64];

    const int lane = threadIdx.x & 63;
    const int wv = threadIdx.x >> 6;
    const int wr = wv >> 1;
    const int wc = wv & 1;
    const int r0 = blockIdx.y * 128;
    const int c0 = blockIdx.x * 128;
    const int rf = lane & 15;
    const int kg = lane >> 4;

    const int NT = K >> 6;

    auto stage = [&](const __hip_bfloat16* src, int rowbase, int kb, short* dst) {
#pragma unroll
        for (int q = 0; q < 4; ++q) {
            const int L = wv * 256 + q * 64 + lane;
            const int r = L >> 3;
            const int cs = (L & 7) ^ (r & 7);
            g2l16(src + (size_t)(rowbase + r) * K + kb + cs * 8, dst + (size_t)L * 8);
        }
    };
    auto frag = [&](const short* base, int row, int ch) -> bf16x8 {
        return *reinterpret_cast<const bf16x8*>(base + row * 64 + ((ch ^ (row & 7)) << 3));
    };

    f32x4 acc[4][4] = {};

    stage(A, r0, 0, &lds[0][0][0][0]);
    stage(W, c0, 0, &lds[0][1][0][0]);
    __syncthreads();

    int cur = 0;
    for (int t = 0; t < NT; ++t) {
        if (t + 1 < NT) {
            stage(A, r0, (t + 1) * 64, &lds[cur ^ 1][0][0][0]);
            stage(W, c0, (t + 1) * 64, &lds[cur ^ 1][1][0][0]);
        }
        const short* la = &lds[cur][0][0][0];
        const short* lb = &lds[cur][1][0][0];
#pragma unroll
        for (int ks = 0; ks < 2; ++ks) {
            bf16x8 af[4], bfr[4];
#pragma unroll
            for (int i = 0; i < 4; ++i)
                af[i] = frag(la, wr * 64 + i * 16 + rf, ks * 4 + kg);
#pragma unroll
            for (int j = 0; j < 4; ++j)
                bfr[j] = frag(lb, wc * 64 + j * 16 + rf, ks * 4 + kg);
#pragma unroll
            for (int i = 0; i < 4; ++i)
#pragma unroll
                for (int j = 0; j < 4; ++j)
                    acc[i][j] = __builtin_amdgcn_mfma_f32_16x16x32_bf16(af[i], bfr[j], acc[i][j], 0, 0, 0);
        }
        __syncthreads();
        cur ^= 1;
    }

    // C/D layout: col = lane&15, row = (lane>>4)*4 + reg  [m89-verified]
#pragma unroll
    for (int j = 0; j < 4; ++j) {
        const int col = c0 + wc * 64 + j * 16 + rf;
        const float bcol = bias[col];
#pragma unroll
        for (int i = 0; i < 4; ++i) {
#pragma unroll
            for (int r = 0; r < 4; ++r) {
                const int row = r0 + wr * 64 + i * 16 + kg * 4 + r;
                storeC(C + (size_t)row * N + col, acc[i][j][r] + bcol);
            }
        }
    }
}

// natten_kv: block = (8x8 pixel tile) x (one head), 256 threads = 4 waves.
// ONE 28KB LDS buffer time-shared: K for QK^T phase, then V for PV phase.
// V global loads issued BEFORE phase 1 (latency hidden under dot products).
// Softmax entirely in registers: 4-lane group owns 49 weights, 13 per lane
// (ownership idx&3==g); broadcast in PV via static-index __shfl.
// Thread (p, g): pixel p (0..63), dim-quarter g (0..3).
__global__ __launch_bounds__(256, 3) void natten_kv(
    const __hip_bfloat16* __restrict__ qkv,
    const float* __restrict__ rpb,
    __hip_bfloat16* __restrict__ aout)
{
    __shared__ short sKV[196][72];   // 28224 B, stride 144 B (16B-aligned, 2-way bank aliasing only)
    __shared__ float sB[169];        // rpb[h] slice

    const int tid = threadIdx.x;
    const int h = blockIdx.y;
    const int ti = blockIdx.x / 10;
    const int tj = blockIdx.x - ti * 10;
    const int R0 = ti * 8 - 3;
    const int C0 = tj * 8 - 3;

    if (tid < 169) sB[tid] = rpb[h * 169 + tid];

    // ---- Stage K halo into sKV (196 slots x 8 chunks of 16B = 1568 tasks)
#pragma unroll
    for (int it = 0; it < 7; ++it) {
        const int task = it * 256 + tid;
        if (task < 1568) {
            const int slot = task >> 3, ch = task & 7;
            const int r = slot / 14, c = slot - r * 14;
            int gi = R0 + r; gi = gi < 0 ? 0 : (gi > 79 ? 79 : gi);
            int gj = C0 + c; gj = gj < 0 ? 0 : (gj > 79 ? 79 : gj);
            bf16x8 kv = *reinterpret_cast<const bf16x8*>(
                qkv + ((size_t)(gi * WW + gj) * 1536 + 512 + h * 64 + ch * 8));
            *reinterpret_cast<bf16x8*>(&sKV[slot][ch * 8]) = kv;
        }
    }
    __syncthreads();

    // ---- Issue V global loads now; consumed after next barrier (T14 split).
    bf16x8 vbuf[7];
#pragma unroll
    for (int it = 0; it < 7; ++it) {
        const int task = it * 256 + tid;
        if (task < 1568) {
            const int slot = task >> 3, ch = task & 7;
            const int r = slot / 14, c = slot - r * 14;
            int gi = R0 + r; gi = gi < 0 ? 0 : (gi > 79 ? 79 : gi);
            int gj = C0 + c; gj = gj < 0 ? 0 : (gj > 79 ? 79 : gj);
            vbuf[it] = *reinterpret_cast<const bf16x8*>(
                qkv + ((size_t)(gi * WW + gj) * 1536 + 1024 + h * 64 + ch * 8));
        }
    }

    const int lane = tid & 63;
    const int wv = tid >> 6;
    const int p = wv * 16 + (lane >> 2);   // tile-local pixel 0..63
    const int g = lane & 3;                // dim quarter
    const int pi = ti * 8 + (p >> 3);
    const int pj = tj * 8 + (p & 7);
    int si = pi - 3; si = si < 0 ? 0 : (si > (HH - KW) ? (HH - KW) : si);
    int sj = pj - 3; sj = sj < 0 ? 0 : (sj > (WW - KW) ? (WW - KW) : sj);
    const int si_l = si - R0;
    const int sj_l = sj - C0;
    const int oh = si - pi + 6;
    const int ow = sj - pj + 6;

    // q fragment (16 dims) with 1/8 scale folded in
    float qf[16];
    {
        const __hip_bfloat16* qsrc =
            qkv + ((size_t)(pi * WW + pj) * 1536 + h * 64 + g * 16);
        bf16x8 q0 = *reinterpret_cast<const bf16x8*>(qsrc);
        bf16x8 q1 = *reinterpret_cast<const bf16x8*>(qsrc + 8);
#pragma unroll
        for (int j = 0; j < 8; ++j) {
            qf[j] = 0.125f * bf2f(q0[j]);
            qf[8 + j] = 0.125f * bf2f(q1[j]);
        }
    }

    // ---- Phase 1: 49 logits; lane g owns idx where idx&3==g (13 regs/lane)
    float wreg[13];
#pragma unroll
    for (int k = 0; k < 13; ++k) wreg[k] = -1e30f;

#pragma unroll
    for (int idx = 0; idx < 49; ++idx) {
        const int a = idx / 7, c = idx % 7;
        const int slot = (si_l + a) * 14 + (sj_l + c);
        bf16x8 k0 = *reinterpret_cast<const bf16x8*>(&sKV[slot][g * 16]);
        bf16x8 k1 = *reinterpret_cast<const bf16x8*>(&sKV[slot][g * 16 + 8]);
        float d = 0.f;
#pragma unroll
        for (int j = 0; j < 8; ++j) d += qf[j] * bf2f(k0[j]);
#pragma unroll
        for (int j = 0; j < 8; ++j) d += qf[8 + j] * bf2f(k1[j]);
        d += __shfl_xor(d, 1, 64);
        d += __shfl_xor(d, 2, 64);     // all 4 g-lanes now hold full dot
        if ((idx & 3) == g)
            wreg[idx >> 2] = d + sB[(oh + a) * 13 + (ow + c)];
    }

    __syncthreads();   // all waves done reading K

    // ---- Write V into sKV (vbuf already in flight / arrived)
#pragma unroll
    for (int it = 0; it < 7; ++it) {
        const int task = it * 256 + tid;
        if (task < 1568) {
            const int slot = task >> 3, ch = task & 7;
            *reinterpret_cast<bf16x8*>(&sKV[slot][ch * 8]) = vbuf[it];
        }
    }

    // ---- Phase 2: softmax in registers (overlaps V ds_write latency)
    float m = wreg[0];
#pragma unroll
    for (int k = 1; k < 13; ++k) m = fmaxf(m, wreg[k]);
    m = fmaxf(m, __shfl_xor(m, 1, 64));
    m = fmaxf(m, __shfl_xor(m, 2, 64));
    float s = 0.f;
#pragma unroll
    for (int k = 0; k < 13; ++k) {
        const float e = __expf(wreg[k] - m);   // -1e30 entries -> exp ~ 0
        wreg[k] = e;
        s += e;
    }
    s += __shfl_xor(s, 1, 64);
    s += __shfl_xor(s, 2, 64);
    const float rs = 1.0f / s;

    __syncthreads();   // V visible to all

    // ---- Phase 3: o[d] = sum_idx w_idx * V[slot_idx][d]
    float o[16];
#pragma unroll
    for (int j = 0; j < 16; ++j) o[j] = 0.f;
#pragma unroll
    for (int idx = 0; idx < 49; ++idx) {
        const int a = idx / 7, c = idx % 7;
        const int slot = (si_l + a) * 14 + (sj_l + c);
        const float w = __shfl(wreg[idx >> 2], (lane & 60) | (idx & 3), 64);
        bf16x8 v0 = *reinterpret_cast<const bf16x8*>(&sKV[slot][g * 16]);
        bf16x8 v1 = *reinterpret_cast<const bf16x8*>(&sKV[slot][g * 16 + 8]);
#pragma unroll
        for (int j = 0; j < 8; ++j) o[j] += w * bf2f(v0[j]);
#pragma unroll
        for (int j = 0; j < 8; ++j) o[8 + j] += w * bf2f(v1[j]);
    }

    bf16x8 r0v, r1v;
#pragma unroll
    for (int j = 0; j < 8; ++j) {
        r0v[j] = (short)f2bf(o[j] * rs);
        r1v[j] = (short)f2bf(o[8 + j] * rs);
    }
    __hip_bfloat16* dst = aout + ((size_t)(pi * WW + pj) * 512 + h * 64 + g * 16);
    *reinterpret_cast<bf16x8*>(dst) = r0v;
    *reinterpret_cast<bf16x8*>(dst + 8) = r1v;
}

extern "C" void kernel_launch(void* const* d_in, const int* in_sizes, int n_in,
                              void* d_out, int out_size, void* d_ws, size_t ws_size,
                              hipStream_t stream) {
    const float* x      = (const float*)d_in[0];
    const float* qkv_w  = (const float*)d_in[1];
    const float* qkv_b  = (const float*)d_in[2];
    const float* rpb    = (const float*)d_in[3];
    const float* proj_w = (const float*)d_in[4];
    const float* proj_b = (const float*)d_in[5];
    float* out = (float*)d_out;

    // ws layout (all bf16): xb | wqkv | wproj | qkv | aout  = 34.9 MB total
    char* wsb = (char*)d_ws;
    __hip_bfloat16* xb    = (__hip_bfloat16*)wsb;                 // 6,553,600 B
    __hip_bfloat16* wqkv  = (__hip_bfloat16*)(wsb + 6553600);     // 1,572,864 B
    __hip_bfloat16* wproj = (__hip_bfloat16*)(wsb + 8126464);     //   524,288 B
    __hip_bfloat16* qkv   = (__hip_bfloat16*)(wsb + 8650752);     // 19,660,800 B
    __hip_bfloat16* aout  = (__hip_bfloat16*)(wsb + 28311552);    // 6,553,600 B

    dim3 blk(256);
    cast3_f32_bf16<<<dim3((819200 + 196608 + 65536 + 255) / 256), blk, 0, stream>>>(
        x, (short*)xb, 819200, qkv_w, (short*)wqkv, 196608, proj_w, (short*)wproj, 65536);

    gemm_lds<__hip_bfloat16><<<dim3((3 * DIM) / 128, NPIX / 128), blk, 0, stream>>>(
        xb, wqkv, qkv_b, qkv, NPIX, 3 * DIM, DIM);

    natten_kv<<<dim3(100, 8), blk, 0, stream>>>(qkv, rpb, aout);

    gemm_lds<float><<<dim3(DIM / 128, NPIX / 128), blk, 0, stream>>>(
        aout, wproj, proj_b, out, NPIX, DIM, DIM);
}

// Round 9
// 127.229 us; speedup vs baseline: 1.2976x; 1.1303x over previous
//
#include <hip/hip_runtime.h>
#include <hip/hip_bf16.h>

// Nat2D neighborhood attention, MI355X gfx950.
// Device ABI: f32 in/out. bf16 MFMA everywhere (GEMMs + natten).
// Pipeline: [cast3 -> bf16] -> [gemm_lds QKV -> bf16 qkv] ->
//           [natten_mfma: S=Q·K^T and O=P·V on MFMA, LDS time-shared] ->
//           [gemm_lds proj -> f32 out]

typedef __attribute__((ext_vector_type(4))) float f32x4;
typedef __attribute__((ext_vector_type(8))) short bf16x8;
typedef __attribute__((ext_vector_type(4))) short s16x4;

#define HEADS 8
#define HEAD_DIM 64
#define DIM 512
#define KW 7
#define HH 80
#define WW 80
#define NPIX (HH * WW)

__device__ inline unsigned short f2bf(float f) {
    union { __hip_bfloat16 b; unsigned short u; } cvt;
    cvt.b = __float2bfloat16(f);
    return cvt.u;
}
__device__ inline float bf2f(short s) {
    union { float f; unsigned u; } c;
    c.u = ((unsigned)(unsigned short)s) << 16;
    return c.f;
}

__device__ inline void storeC(float* p, float v) { *p = v; }
__device__ inline void storeC(__hip_bfloat16* p, float v) { *p = __float2bfloat16(v); }

// async global->LDS, 16B per lane. LDS dest must be linear in lane order.
__device__ inline void g2l16(const void* g, void* l) {
    __builtin_amdgcn_global_load_lds(
        (const __attribute__((address_space(1))) unsigned int*)g,
        (__attribute__((address_space(3))) unsigned int*)l,
        16, 0, 0);
}

// Fused f32 -> bf16 cast for three arrays (x, qkv_w, proj_w).
__global__ __launch_bounds__(256) void cast3_f32_bf16(
    const float* __restrict__ a, short* __restrict__ oa, int na4,
    const float* __restrict__ b, short* __restrict__ ob, int nb4,
    const float* __restrict__ c, short* __restrict__ oc, int nc4)
{
    int i = blockIdx.x * 256 + threadIdx.x;
    const float* src; short* dst; int idx;
    if (i < na4) { src = a; dst = oa; idx = i; }
    else if (i < na4 + nb4) { src = b; dst = ob; idx = i - na4; }
    else if (i < na4 + nb4 + nc4) { src = c; dst = oc; idx = i - na4 - nb4; }
    else return;
    f32x4 v = reinterpret_cast<const f32x4*>(src)[idx];
    s16x4 r;
#pragma unroll
    for (int j = 0; j < 4; ++j) r[j] = (short)f2bf(v[j]);
    reinterpret_cast<s16x4*>(dst)[idx] = r;
}

// C[m,n] = sum_k A[m,k] * W[n,k] + bias[n]   (A @ W^T + b)
// 128x128 tile, BK=64, 4 waves in 2x2 quadrants, dbuf LDS via
// global_load_lds(16B), XOR-swizzle on SOURCE + ds_read (rule #21).
template <typename CT>
__global__ __launch_bounds__(256) void gemm_lds(
    const __hip_bfloat16* __restrict__ A,
    const __hip_bfloat16* __restrict__ W,
    const float* __restrict__ bias,
    CT* __restrict__ C,
    int M, int N, int K)
{
    __shared__ short lds[2][2][128][64];

    const int lane = threadIdx.x & 63;
    const int wv = threadIdx.x >> 6;
    const int wr = wv >> 1;
    const int wc = wv & 1;
    const int r0 = blockIdx.y * 128;
    const int c0 = blockIdx.x * 128;
    const int rf = lane & 15;
    const int kg = lane >> 4;

    const int NT = K >> 6;

    auto stage = [&](const __hip_bfloat16* src, int rowbase, int kb, short* dst) {
#pragma unroll
        for (int q = 0; q < 4; ++q) {
            const int L = wv * 256 + q * 64 + lane;
            const int r = L >> 3;
            const int cs = (L & 7) ^ (r & 7);
            g2l16(src + (size_t)(rowbase + r) * K + kb + cs * 8, dst + (size_t)L * 8);
        }
    };
    auto frag = [&](const short* base, int row, int ch) -> bf16x8 {
        return *reinterpret_cast<const bf16x8*>(base + row * 64 + ((ch ^ (row & 7)) << 3));
    };

    f32x4 acc[4][4] = {};

    stage(A, r0, 0, &lds[0][0][0][0]);
    stage(W, c0, 0, &lds[0][1][0][0]);
    __syncthreads();

    int cur = 0;
    for (int t = 0; t < NT; ++t) {
        if (t + 1 < NT) {
            stage(A, r0, (t + 1) * 64, &lds[cur ^ 1][0][0][0]);
            stage(W, c0, (t + 1) * 64, &lds[cur ^ 1][1][0][0]);
        }
        const short* la = &lds[cur][0][0][0];
        const short* lb = &lds[cur][1][0][0];
#pragma unroll
        for (int ks = 0; ks < 2; ++ks) {
            bf16x8 af[4], bfr[4];
#pragma unroll
            for (int i = 0; i < 4; ++i)
                af[i] = frag(la, wr * 64 + i * 16 + rf, ks * 4 + kg);
#pragma unroll
            for (int j = 0; j < 4; ++j)
                bfr[j] = frag(lb, wc * 64 + j * 16 + rf, ks * 4 + kg);
#pragma unroll
            for (int i = 0; i < 4; ++i)
#pragma unroll
                for (int j = 0; j < 4; ++j)
                    acc[i][j] = __builtin_amdgcn_mfma_f32_16x16x32_bf16(af[i], bfr[j], acc[i][j], 0, 0, 0);
        }
        __syncthreads();
        cur ^= 1;
    }

    // C/D layout: col = lane&15, row = (lane>>4)*4 + reg  [m89-verified]
#pragma unroll
    for (int j = 0; j < 4; ++j) {
        const int col = c0 + wc * 64 + j * 16 + rf;
        const float bcol = bias[col];
#pragma unroll
        for (int i = 0; i < 4; ++i) {
#pragma unroll
            for (int r = 0; r < 4; ++r) {
                const int row = r0 + wr * 64 + i * 16 + kg * 4 + r;
                storeC(C + (size_t)row * N + col, acc[i][j][r] + bcol);
            }
        }
    }
}

// natten_mfma: block = (8x8 pixel tile) x (one head), 256 threads = 4 waves.
// S = Q(64x64)·K^T(208x64) via MFMA; bias+mask+softmax per-row (rs stays in
// regs since S and O share the C/D row mapping); P -> LDS (A-layout);
// V^T -> LDS (B-layout, [d][slot]); O = P·V via MFMA + VALU tail (slots
// 192..195). LDS time-shared: region1 {K then P}, region2 {Q+rpb then V^T}.
// 52 KB total -> 3 blocks/CU.
__global__ __launch_bounds__(256, 3) void natten_mfma(
    const __hip_bfloat16* __restrict__ qkv,
    const float* __restrict__ rpb,
    __hip_bfloat16* __restrict__ aout)
{
    __shared__ __align__(16) short reg1[13312];  // sK [208][64] swz -> sP [64][208]
    __shared__ __align__(16) short reg2[13312];  // sQ [64][64] swz + sB -> sVT [64][208]
    short* sK  = reg1;
    short* sP  = reg1;
    short* sQ  = reg2;
    float* sB  = (float*)(reg2 + 4096);          // bytes 8192..8868, after sQ
    short* sVT = reg2;

    const int tid = threadIdx.x;
    const int lane = tid & 63;
    const int wv = tid >> 6;
    const int l15 = lane & 15;
    const int kg = lane >> 4;
    const int h = blockIdx.y;
    const int ti = blockIdx.x / 10;
    const int tj = blockIdx.x - ti * 10;
    const int R0 = ti * 8 - 3;
    const int C0 = tj * 8 - 3;

    if (tid < 169) sB[tid] = rpb[h * 169 + tid];

    // ---- Stage Q (64 rows x 8 chunks = 512 tasks), XOR-swizzled source
#pragma unroll
    for (int i = 0; i < 2; ++i) {
        const int L = i * 256 + tid;
        const int row = L >> 3, ch = L & 7;
        const int pi = ti * 8 + (row >> 3), pjg = tj * 8 + (row & 7);
        const int cs = ch ^ (row & 7);
        g2l16(qkv + ((size_t)(pi * WW + pjg) * 1536 + h * 64 + cs * 8),
              sQ + (size_t)L * 8);
    }
    // ---- Stage K halo (196 slots x 8 chunks = 1568 tasks), swizzled
#pragma unroll
    for (int i = 0; i < 7; ++i) {
        const int t = i * 256 + tid;
        if (t < 1568) {
            const int slot = t >> 3, ch = t & 7;
            const int r = slot / 14, c = slot - r * 14;
            int gi = R0 + r; gi = gi < 0 ? 0 : (gi > 79 ? 79 : gi);
            int gj = C0 + c; gj = gj < 0 ? 0 : (gj > 79 ? 79 : gj);
            const int cs = ch ^ (slot & 7);
            g2l16(qkv + ((size_t)(gi * WW + gj) * 1536 + 512 + h * 64 + cs * 8),
                  sK + (size_t)t * 8);
        }
    }
    __syncthreads();   // bar1: Q,K,sB ready

    // ---- Issue V loads to regs now (consumed after bar2; hides under S)
    bf16x8 vbuf[7];
#pragma unroll
    for (int i = 0; i < 7; ++i) {
        const int t = i * 256 + tid;
        if (t < 1568) {
            const int slot = t % 196, ch = t / 196;
            const int r = slot / 14, c = slot - r * 14;
            int gi = R0 + r; gi = gi < 0 ? 0 : (gi > 79 ? 79 : gi);
            int gj = C0 + c; gj = gj < 0 ? 0 : (gj > 79 ? 79 : gj);
            vbuf[i] = *reinterpret_cast<const bf16x8*>(
                qkv + ((size_t)(gi * WW + gj) * 1536 + 1024 + h * 64 + ch * 8));
        }
    }

    auto fragswz = [&](const short* base, int row, int ch) -> bf16x8 {
        return *reinterpret_cast<const bf16x8*>(base + row * 64 + ((ch ^ (row & 7)) << 3));
    };

    // ---- S = Q·K^T  (wave wv owns m-tile wv: rows wv*16..+15)
    f32x4 acc[13];
#pragma unroll
    for (int nt = 0; nt < 13; ++nt) acc[nt] = f32x4{0.f, 0.f, 0.f, 0.f};
    {
        bf16x8 aq0 = fragswz(sQ, wv * 16 + l15, kg);
        bf16x8 aq1 = fragswz(sQ, wv * 16 + l15, 4 + kg);
#pragma unroll
        for (int nt = 0; nt < 13; ++nt) {
            bf16x8 bk0 = fragswz(sK, nt * 16 + l15, kg);
            bf16x8 bk1 = fragswz(sK, nt * 16 + l15, 4 + kg);
            acc[nt] = __builtin_amdgcn_mfma_f32_16x16x32_bf16(aq0, bk0, acc[nt], 0, 0, 0);
            acc[nt] = __builtin_amdgcn_mfma_f32_16x16x32_bf16(aq1, bk1, acc[nt], 0, 0, 0);
        }
    }

    // ---- bias + mask + softmax (C/D: row = kg*4+reg, col = nt*16+l15)
    int pil[4], pjl[4], sil[4], sjl[4];
#pragma unroll
    for (int rg = 0; rg < 4; ++rg) {
        const int px = wv * 16 + kg * 4 + rg;
        const int pl = px >> 3, pw = px & 7;
        const int pi = ti * 8 + pl, pjg = tj * 8 + pw;
        int si = pi - 3; si = si < 0 ? 0 : (si > 73 ? 73 : si);
        int sj = pjg - 3; sj = sj < 0 ? 0 : (sj > 73 ? 73 : sj);
        pil[rg] = pl; pjl[rg] = pw;
        sil[rg] = si - R0; sjl[rg] = sj - C0;
    }
    float m4[4] = {-1e30f, -1e30f, -1e30f, -1e30f};
#pragma unroll
    for (int nt = 0; nt < 13; ++nt) {
        const int slot = nt * 16 + l15;
        const int r = slot / 14, c = slot - (slot / 14) * 14;
        const bool sv = slot < 196;
#pragma unroll
        for (int rg = 0; rg < 4; ++rg) {
            const unsigned a = (unsigned)(r - sil[rg]);
            const unsigned b = (unsigned)(c - sjl[rg]);
            float lv = -1e30f;
            if (sv && a < 7u && b < 7u)
                lv = 0.125f * acc[nt][rg] +
                     sB[(r - pil[rg] + 3) * 13 + (c - pjl[rg] + 3)];
            acc[nt][rg] = lv;
            m4[rg] = fmaxf(m4[rg], lv);
        }
    }
#pragma unroll
    for (int rg = 0; rg < 4; ++rg) {
        m4[rg] = fmaxf(m4[rg], __shfl_xor(m4[rg], 1, 64));
        m4[rg] = fmaxf(m4[rg], __shfl_xor(m4[rg], 2, 64));
        m4[rg] = fmaxf(m4[rg], __shfl_xor(m4[rg], 4, 64));
        m4[rg] = fmaxf(m4[rg], __shfl_xor(m4[rg], 8, 64));
    }
    float s4[4] = {0.f, 0.f, 0.f, 0.f};
#pragma unroll
    for (int nt = 0; nt < 13; ++nt)
#pragma unroll
        for (int rg = 0; rg < 4; ++rg) {
            const float e = __expf(acc[nt][rg] - m4[rg]);
            acc[nt][rg] = e;
            s4[rg] += e;
        }
#pragma unroll
    for (int rg = 0; rg < 4; ++rg) {
        s4[rg] += __shfl_xor(s4[rg], 1, 64);
        s4[rg] += __shfl_xor(s4[rg], 2, 64);
        s4[rg] += __shfl_xor(s4[rg], 4, 64);
        s4[rg] += __shfl_xor(s4[rg], 8, 64);
    }
    float rs[4];
#pragma unroll
    for (int rg = 0; rg < 4; ++rg) rs[rg] = 1.0f / s4[rg];

    __syncthreads();   // bar2: everyone done reading sK/sQ/sB

    // ---- Write P (bf16, un-normalized exp) to sP [64][208]
#pragma unroll
    for (int nt = 0; nt < 13; ++nt) {
        const int slot = nt * 16 + l15;
#pragma unroll
        for (int rg = 0; rg < 4; ++rg) {
            const int px = wv * 16 + kg * 4 + rg;
            sP[px * 208 + slot] = (short)f2bf(acc[nt][rg]);
        }
    }
    // ---- Write V^T [d][slot] from vbuf; zero cols 196..207
#pragma unroll
    for (int i = 0; i < 7; ++i) {
        const int t = i * 256 + tid;
        if (t < 1568) {
            const int slot = t % 196, ch = t / 196;
#pragma unroll
            for (int j = 0; j < 8; ++j)
                sVT[(ch * 8 + j) * 208 + slot] = vbuf[i][j];
        }
    }
#pragma unroll
    for (int i = 0; i < 3; ++i) {
        const int idx = i * 256 + tid;
        if (idx < 768) sVT[(idx / 12) * 208 + 196 + (idx - (idx / 12) * 12)] = 0;
    }
    __syncthreads();   // bar3: P, V^T ready

    // ---- O = P·V  (wave wv: m-tile wv, 4 n-tiles, k = 0..191 MFMA)
    f32x4 oacc[4];
#pragma unroll
    for (int nt = 0; nt < 4; ++nt) oacc[nt] = f32x4{0.f, 0.f, 0.f, 0.f};
#pragma unroll
    for (int ks = 0; ks < 6; ++ks) {
        bf16x8 ap = *reinterpret_cast<const bf16x8*>(
            sP + (wv * 16 + l15) * 208 + (ks * 4 + kg) * 8);
#pragma unroll
        for (int nt = 0; nt < 4; ++nt) {
            bf16x8 bv = *reinterpret_cast<const bf16x8*>(
                sVT + (nt * 16 + l15) * 208 + (ks * 4 + kg) * 8);
            oacc[nt] = __builtin_amdgcn_mfma_f32_16x16x32_bf16(ap, bv, oacc[nt], 0, 0, 0);
        }
    }
    // ---- VALU tail: slots 192..195 (P cols 196..207 are zero by mask)
#pragma unroll
    for (int s = 192; s < 196; ++s) {
        float pw[4];
#pragma unroll
        for (int rg = 0; rg < 4; ++rg)
            pw[rg] = bf2f(sP[(wv * 16 + kg * 4 + rg) * 208 + s]);
#pragma unroll
        for (int nt = 0; nt < 4; ++nt) {
            const float vv = bf2f(sVT[(nt * 16 + l15) * 208 + s]);
#pragma unroll
            for (int rg = 0; rg < 4; ++rg)
                oacc[nt][rg] += pw[rg] * vv;
        }
    }

    // ---- Epilogue: O row rg uses rs[rg] (same C/D row mapping as S)
#pragma unroll
    for (int rg = 0; rg < 4; ++rg) {
        const int px = wv * 16 + kg * 4 + rg;
        const int pi = ti * 8 + (px >> 3), pjg = tj * 8 + (px & 7);
        __hip_bfloat16* dst = aout + (size_t)(pi * WW + pjg) * 512 + h * 64;
        const float rsv = rs[rg];
#pragma unroll
        for (int nt = 0; nt < 4; ++nt)
            dst[nt * 16 + l15] = __float2bfloat16(oacc[nt][rg] * rsv);
    }
}

extern "C" void kernel_launch(void* const* d_in, const int* in_sizes, int n_in,
                              void* d_out, int out_size, void* d_ws, size_t ws_size,
                              hipStream_t stream) {
    const float* x      = (const float*)d_in[0];
    const float* qkv_w  = (const float*)d_in[1];
    const float* qkv_b  = (const float*)d_in[2];
    const float* rpb    = (const float*)d_in[3];
    const float* proj_w = (const float*)d_in[4];
    const float* proj_b = (const float*)d_in[5];
    float* out = (float*)d_out;

    // ws layout (all bf16): xb | wqkv | wproj | qkv | aout  = 34.9 MB total
    char* wsb = (char*)d_ws;
    __hip_bfloat16* xb    = (__hip_bfloat16*)wsb;                 // 6,553,600 B
    __hip_bfloat16* wqkv  = (__hip_bfloat16*)(wsb + 6553600);     // 1,572,864 B
    __hip_bfloat16* wproj = (__hip_bfloat16*)(wsb + 8126464);     //   524,288 B
    __hip_bfloat16* qkv   = (__hip_bfloat16*)(wsb + 8650752);     // 19,660,800 B
    __hip_bfloat16* aout  = (__hip_bfloat16*)(wsb + 28311552);    // 6,553,600 B

    dim3 blk(256);
    cast3_f32_bf16<<<dim3((819200 + 196608 + 65536 + 255) / 256), blk, 0, stream>>>(
        x, (short*)xb, 819200, qkv_w, (short*)wqkv, 196608, proj_w, (short*)wproj, 65536);

    gemm_lds<__hip_bfloat16><<<dim3((3 * DIM) / 128, NPIX / 128), blk, 0, stream>>>(
        xb, wqkv, qkv_b, qkv, NPIX, 3 * DIM, DIM);

    natten_mfma<<<dim3(100, 8), blk, 0, stream>>>(qkv, rpb, aout);

    gemm_lds<float><<<dim3(DIM / 128, NPIX / 128), blk, 0, stream>>>(
        aout, wproj, proj_b, out, NPIX, DIM, DIM);
}

// Round 10
// 126.624 us; speedup vs baseline: 1.3037x; 1.0048x over previous
//
#include <hip/hip_runtime.h>
#include <hip/hip_bf16.h>

// Nat2D neighborhood attention, MI355X gfx950.
// Device ABI: f32 in/out. bf16 MFMA everywhere (GEMMs + natten).
// Pipeline: [cast3 -> bf16] -> [gemm_sb<64,128> QKV -> bf16 qkv] ->
//           [natten_mfma] -> [gemm_sb<64,64> proj -> f32 out]
// gemm_sb = m97-style single-buffer LDS staging (2 barriers/K-step),
// tile sized for grid parallelism (QKV 1200 blocks, proj 800 blocks).

typedef __attribute__((ext_vector_type(4))) float f32x4;
typedef __attribute__((ext_vector_type(8))) short bf16x8;
typedef __attribute__((ext_vector_type(4))) short s16x4;

#define HEADS 8
#define HEAD_DIM 64
#define DIM 512
#define KW 7
#define HH 80
#define WW 80
#define NPIX (HH * WW)

__device__ inline unsigned short f2bf(float f) {
    union { __hip_bfloat16 b; unsigned short u; } cvt;
    cvt.b = __float2bfloat16(f);
    return cvt.u;
}
__device__ inline float bf2f(short s) {
    union { float f; unsigned u; } c;
    c.u = ((unsigned)(unsigned short)s) << 16;
    return c.f;
}

__device__ inline void storeC(float* p, float v) { *p = v; }
__device__ inline void storeC(__hip_bfloat16* p, float v) { *p = __float2bfloat16(v); }

// async global->LDS, 16B per lane. LDS dest must be linear in lane order.
__device__ inline void g2l16(const void* g, void* l) {
    __builtin_amdgcn_global_load_lds(
        (const __attribute__((address_space(1))) unsigned int*)g,
        (__attribute__((address_space(3))) unsigned int*)l,
        16, 0, 0);
}

// Fused f32 -> bf16 cast for three arrays (x, qkv_w, proj_w).
__global__ __launch_bounds__(256) void cast3_f32_bf16(
    const float* __restrict__ a, short* __restrict__ oa, int na4,
    const float* __restrict__ b, short* __restrict__ ob, int nb4,
    const float* __restrict__ c, short* __restrict__ oc, int nc4)
{
    int i = blockIdx.x * 256 + threadIdx.x;
    const float* src; short* dst; int idx;
    if (i < na4) { src = a; dst = oa; idx = i; }
    else if (i < na4 + nb4) { src = b; dst = ob; idx = i - na4; }
    else if (i < na4 + nb4 + nc4) { src = c; dst = oc; idx = i - na4 - nb4; }
    else return;
    f32x4 v = reinterpret_cast<const f32x4*>(src)[idx];
    s16x4 r;
#pragma unroll
    for (int j = 0; j < 4; ++j) r[j] = (short)f2bf(v[j]);
    reinterpret_cast<s16x4*>(dst)[idx] = r;
}

// C[m,n] = sum_k A[m,k] * W[n,k] + bias[n]   (A @ W^T + b)
// m97-style single-buffer: stage(BK=64) -> barrier -> MFMA -> barrier.
// 4 waves in 2x2 quadrants of (BM/2 x BN/2). XOR-swizzle on SOURCE addr
// + same XOR on ds_read (rule #21; LDS dest stays linear for g2l16).
// Requires M%BM==0, N%BN==0, K%64==0.
template <int BM, int BN, typename CT>
__global__ __launch_bounds__(256) void gemm_sb(
    const __hip_bfloat16* __restrict__ A,
    const __hip_bfloat16* __restrict__ W,
    const float* __restrict__ bias,
    CT* __restrict__ C,
    int M, int N, int K)
{
    constexpr int WM = BM / 2, WN = BN / 2;
    constexpr int MI = WM / 16, NI = WN / 16;
    __shared__ __align__(16) short lds[(BM + BN) * 64];
    short* sA = lds;
    short* sB2 = lds + BM * 64;

    const int tid = threadIdx.x;
    const int lane = tid & 63;
    const int wv = tid >> 6;
    const int wr = wv >> 1;
    const int wc = wv & 1;
    const int r0 = blockIdx.y * BM;
    const int c0 = blockIdx.x * BN;
    const int rf = lane & 15;
    const int kg = lane >> 4;
    const int NT = K >> 6;

    // stage a [ROWS][64] bf16 panel; source chunk pre-swizzled, LDS linear
    auto stage = [&](const __hip_bfloat16* src, int rowbase, int kb,
                     short* dst, int ntasks) {
        for (int q = 0; q < ntasks / 256; ++q) {
            const int L = q * 256 + tid;      // 16B-slot index
            const int r = L >> 3;
            const int cs = (L & 7) ^ (r & 7);
            g2l16(src + (size_t)(rowbase + r) * K + kb + cs * 8, dst + (size_t)L * 8);
        }
    };
    auto frag = [&](const short* base, int row, int ch) -> bf16x8 {
        return *reinterpret_cast<const bf16x8*>(base + row * 64 + ((ch ^ (row & 7)) << 3));
    };

    f32x4 acc[MI][NI] = {};

    for (int t = 0; t < NT; ++t) {
        stage(A, r0, t * 64, sA, BM * 8);
        stage(W, c0, t * 64, sB2, BN * 8);
        __syncthreads();                     // vmcnt(0) drain -> panels ready
#pragma unroll
        for (int ks = 0; ks < 2; ++ks) {
            bf16x8 af[MI], bfr[NI];
#pragma unroll
            for (int i = 0; i < MI; ++i)
                af[i] = frag(sA, wr * WM + i * 16 + rf, ks * 4 + kg);
#pragma unroll
            for (int j = 0; j < NI; ++j)
                bfr[j] = frag(sB2, wc * WN + j * 16 + rf, ks * 4 + kg);
#pragma unroll
            for (int i = 0; i < MI; ++i)
#pragma unroll
                for (int j = 0; j < NI; ++j)
                    acc[i][j] = __builtin_amdgcn_mfma_f32_16x16x32_bf16(af[i], bfr[j], acc[i][j], 0, 0, 0);
        }
        __syncthreads();                     // all reads done before re-stage
    }

    // C/D layout: col = lane&15, row = (lane>>4)*4 + reg  [m89-verified]
#pragma unroll
    for (int j = 0; j < NI; ++j) {
        const int col = c0 + wc * WN + j * 16 + rf;
        const float bcol = bias[col];
#pragma unroll
        for (int i = 0; i < MI; ++i) {
#pragma unroll
            for (int r = 0; r < 4; ++r) {
                const int row = r0 + wr * WM + i * 16 + kg * 4 + r;
                storeC(C + (size_t)row * N + col, acc[i][j][r] + bcol);
            }
        }
    }
}

// natten_mfma: block = (8x8 pixel tile) x (one head), 256 threads = 4 waves.
// S = Q(64x64)·K^T(208x64) via MFMA; bias+mask+softmax per-row; P -> LDS;
// V^T -> LDS; O = P·V via MFMA + VALU tail. LDS time-shared, 52 KB.
__global__ __launch_bounds__(256, 3) void natten_mfma(
    const __hip_bfloat16* __restrict__ qkv,
    const float* __restrict__ rpb,
    __hip_bfloat16* __restrict__ aout)
{
    __shared__ __align__(16) short reg1[13312];  // sK [208][64] swz -> sP [64][208]
    __shared__ __align__(16) short reg2[13312];  // sQ [64][64] swz + sB -> sVT [64][208]
    short* sK  = reg1;
    short* sP  = reg1;
    short* sQ  = reg2;
    float* sB  = (float*)(reg2 + 4096);
    short* sVT = reg2;

    const int tid = threadIdx.x;
    const int lane = tid & 63;
    const int wv = tid >> 6;
    const int l15 = lane & 15;
    const int kg = lane >> 4;
    const int h = blockIdx.y;
    const int ti = blockIdx.x / 10;
    const int tj = blockIdx.x - ti * 10;
    const int R0 = ti * 8 - 3;
    const int C0 = tj * 8 - 3;

    if (tid < 169) sB[tid] = rpb[h * 169 + tid];

    // Stage Q (64 rows x 8 chunks), XOR-swizzled source
#pragma unroll
    for (int i = 0; i < 2; ++i) {
        const int L = i * 256 + tid;
        const int row = L >> 3, ch = L & 7;
        const int pi = ti * 8 + (row >> 3), pjg = tj * 8 + (row & 7);
        const int cs = ch ^ (row & 7);
        g2l16(qkv + ((size_t)(pi * WW + pjg) * 1536 + h * 64 + cs * 8),
              sQ + (size_t)L * 8);
    }
    // Stage K halo (196 slots x 8 chunks), swizzled
#pragma unroll
    for (int i = 0; i < 7; ++i) {
        const int t = i * 256 + tid;
        if (t < 1568) {
            const int slot = t >> 3, ch = t & 7;
            const int r = slot / 14, c = slot - r * 14;
            int gi = R0 + r; gi = gi < 0 ? 0 : (gi > 79 ? 79 : gi);
            int gj = C0 + c; gj = gj < 0 ? 0 : (gj > 79 ? 79 : gj);
            const int cs = ch ^ (slot & 7);
            g2l16(qkv + ((size_t)(gi * WW + gj) * 1536 + 512 + h * 64 + cs * 8),
                  sK + (size_t)t * 8);
        }
    }
    __syncthreads();   // bar1: Q,K,sB ready

    // Issue V loads to regs (consumed after bar2; hides under S)
    bf16x8 vbuf[7];
#pragma unroll
    for (int i = 0; i < 7; ++i) {
        const int t = i * 256 + tid;
        if (t < 1568) {
            const int slot = t % 196, ch = t / 196;
            const int r = slot / 14, c = slot - r * 14;
            int gi = R0 + r; gi = gi < 0 ? 0 : (gi > 79 ? 79 : gi);
            int gj = C0 + c; gj = gj < 0 ? 0 : (gj > 79 ? 79 : gj);
            vbuf[i] = *reinterpret_cast<const bf16x8*>(
                qkv + ((size_t)(gi * WW + gj) * 1536 + 1024 + h * 64 + ch * 8));
        }
    }

    auto fragswz = [&](const short* base, int row, int ch) -> bf16x8 {
        return *reinterpret_cast<const bf16x8*>(base + row * 64 + ((ch ^ (row & 7)) << 3));
    };

    // S = Q·K^T  (wave wv owns rows wv*16..+15)
    f32x4 acc[13];
#pragma unroll
    for (int nt = 0; nt < 13; ++nt) acc[nt] = f32x4{0.f, 0.f, 0.f, 0.f};
    {
        bf16x8 aq0 = fragswz(sQ, wv * 16 + l15, kg);
        bf16x8 aq1 = fragswz(sQ, wv * 16 + l15, 4 + kg);
#pragma unroll
        for (int nt = 0; nt < 13; ++nt) {
            bf16x8 bk0 = fragswz(sK, nt * 16 + l15, kg);
            bf16x8 bk1 = fragswz(sK, nt * 16 + l15, 4 + kg);
            acc[nt] = __builtin_amdgcn_mfma_f32_16x16x32_bf16(aq0, bk0, acc[nt], 0, 0, 0);
            acc[nt] = __builtin_amdgcn_mfma_f32_16x16x32_bf16(aq1, bk1, acc[nt], 0, 0, 0);
        }
    }

    // bias + mask + softmax (C/D: row = kg*4+reg, col = nt*16+l15)
    int pil[4], pjl[4], sil[4], sjl[4];
#pragma unroll
    for (int rg = 0; rg < 4; ++rg) {
        const int px = wv * 16 + kg * 4 + rg;
        const int pl = px >> 3, pw = px & 7;
        const int pi = ti * 8 + pl, pjg = tj * 8 + pw;
        int si = pi - 3; si = si < 0 ? 0 : (si > 73 ? 73 : si);
        int sj = pjg - 3; sj = sj < 0 ? 0 : (sj > 73 ? 73 : sj);
        pil[rg] = pl; pjl[rg] = pw;
        sil[rg] = si - R0; sjl[rg] = sj - C0;
    }
    float m4[4] = {-1e30f, -1e30f, -1e30f, -1e30f};
#pragma unroll
    for (int nt = 0; nt < 13; ++nt) {
        const int slot = nt * 16 + l15;
        const int r = slot / 14, c = slot - (slot / 14) * 14;
        const bool sv = slot < 196;
#pragma unroll
        for (int rg = 0; rg < 4; ++rg) {
            const unsigned a = (unsigned)(r - sil[rg]);
            const unsigned b = (unsigned)(c - sjl[rg]);
            float lv = -1e30f;
            if (sv && a < 7u && b < 7u)
                lv = 0.125f * acc[nt][rg] +
                     sB[(r - pil[rg] + 3) * 13 + (c - pjl[rg] + 3)];
            acc[nt][rg] = lv;
            m4[rg] = fmaxf(m4[rg], lv);
        }
    }
#pragma unroll
    for (int rg = 0; rg < 4; ++rg) {
        m4[rg] = fmaxf(m4[rg], __shfl_xor(m4[rg], 1, 64));
        m4[rg] = fmaxf(m4[rg], __shfl_xor(m4[rg], 2, 64));
        m4[rg] = fmaxf(m4[rg], __shfl_xor(m4[rg], 4, 64));
        m4[rg] = fmaxf(m4[rg], __shfl_xor(m4[rg], 8, 64));
    }
    float s4[4] = {0.f, 0.f, 0.f, 0.f};
#pragma unroll
    for (int nt = 0; nt < 13; ++nt)
#pragma unroll
        for (int rg = 0; rg < 4; ++rg) {
            const float e = __expf(acc[nt][rg] - m4[rg]);
            acc[nt][rg] = e;
            s4[rg] += e;
        }
#pragma unroll
    for (int rg = 0; rg < 4; ++rg) {
        s4[rg] += __shfl_xor(s4[rg], 1, 64);
        s4[rg] += __shfl_xor(s4[rg], 2, 64);
        s4[rg] += __shfl_xor(s4[rg], 4, 64);
        s4[rg] += __shfl_xor(s4[rg], 8, 64);
    }
    float rs[4];
#pragma unroll
    for (int rg = 0; rg < 4; ++rg) rs[rg] = 1.0f / s4[rg];

    __syncthreads();   // bar2: done reading sK/sQ/sB

    // Write P (bf16, un-normalized exp) to sP [64][208]
#pragma unroll
    for (int nt = 0; nt < 13; ++nt) {
        const int slot = nt * 16 + l15;
#pragma unroll
        for (int rg = 0; rg < 4; ++rg) {
            const int px = wv * 16 + kg * 4 + rg;
            sP[px * 208 + slot] = (short)f2bf(acc[nt][rg]);
        }
    }
    // Write V^T [d][slot] from vbuf; zero cols 196..207
#pragma unroll
    for (int i = 0; i < 7; ++i) {
        const int t = i * 256 + tid;
        if (t < 1568) {
            const int slot = t % 196, ch = t / 196;
#pragma unroll
            for (int j = 0; j < 8; ++j)
                sVT[(ch * 8 + j) * 208 + slot] = vbuf[i][j];
        }
    }
#pragma unroll
    for (int i = 0; i < 3; ++i) {
        const int idx = i * 256 + tid;
        if (idx < 768) sVT[(idx / 12) * 208 + 196 + (idx - (idx / 12) * 12)] = 0;
    }
    __syncthreads();   // bar3: P, V^T ready

    // O = P·V
    f32x4 oacc[4];
#pragma unroll
    for (int nt = 0; nt < 4; ++nt) oacc[nt] = f32x4{0.f, 0.f, 0.f, 0.f};
#pragma unroll
    for (int ks = 0; ks < 6; ++ks) {
        bf16x8 ap = *reinterpret_cast<const bf16x8*>(
            sP + (wv * 16 + l15) * 208 + (ks * 4 + kg) * 8);
#pragma unroll
        for (int nt = 0; nt < 4; ++nt) {
            bf16x8 bv = *reinterpret_cast<const bf16x8*>(
                sVT + (nt * 16 + l15) * 208 + (ks * 4 + kg) * 8);
            oacc[nt] = __builtin_amdgcn_mfma_f32_16x16x32_bf16(ap, bv, oacc[nt], 0, 0, 0);
        }
    }
    // VALU tail: slots 192..195
#pragma unroll
    for (int s = 192; s < 196; ++s) {
        float pw[4];
#pragma unroll
        for (int rg = 0; rg < 4; ++rg)
            pw[rg] = bf2f(sP[(wv * 16 + kg * 4 + rg) * 208 + s]);
#pragma unroll
        for (int nt = 0; nt < 4; ++nt) {
            const float vv = bf2f(sVT[(nt * 16 + l15) * 208 + s]);
#pragma unroll
            for (int rg = 0; rg < 4; ++rg)
                oacc[nt][rg] += pw[rg] * vv;
        }
    }

    // Epilogue
#pragma unroll
    for (int rg = 0; rg < 4; ++rg) {
        const int px = wv * 16 + kg * 4 + rg;
        const int pi = ti * 8 + (px >> 3), pjg = tj * 8 + (px & 7);
        __hip_bfloat16* dst = aout + (size_t)(pi * WW + pjg) * 512 + h * 64;
        const float rsv = rs[rg];
#pragma unroll
        for (int nt = 0; nt < 4; ++nt)
            dst[nt * 16 + l15] = __float2bfloat16(oacc[nt][rg] * rsv);
    }
}

extern "C" void kernel_launch(void* const* d_in, const int* in_sizes, int n_in,
                              void* d_out, int out_size, void* d_ws, size_t ws_size,
                              hipStream_t stream) {
    const float* x      = (const float*)d_in[0];
    const float* qkv_w  = (const float*)d_in[1];
    const float* qkv_b  = (const float*)d_in[2];
    const float* rpb    = (const float*)d_in[3];
    const float* proj_w = (const float*)d_in[4];
    const float* proj_b = (const float*)d_in[5];
    float* out = (float*)d_out;

    // ws layout (all bf16): xb | wqkv | wproj | qkv | aout  = 34.9 MB total
    char* wsb = (char*)d_ws;
    __hip_bfloat16* xb    = (__hip_bfloat16*)wsb;                 // 6,553,600 B
    __hip_bfloat16* wqkv  = (__hip_bfloat16*)(wsb + 6553600);     // 1,572,864 B
    __hip_bfloat16* wproj = (__hip_bfloat16*)(wsb + 8126464);     //   524,288 B
    __hip_bfloat16* qkv   = (__hip_bfloat16*)(wsb + 8650752);     // 19,660,800 B
    __hip_bfloat16* aout  = (__hip_bfloat16*)(wsb + 28311552);    // 6,553,600 B

    dim3 blk(256);
    cast3_f32_bf16<<<dim3((819200 + 196608 + 65536 + 255) / 256), blk, 0, stream>>>(
        x, (short*)xb, 819200, qkv_w, (short*)wqkv, 196608, proj_w, (short*)wproj, 65536);

    // QKV: M=6400, N=1536, K=512. BM=64 x BN=128 -> grid 12 x 100 = 1200 blocks.
    gemm_sb<64, 128, __hip_bfloat16><<<dim3((3 * DIM) / 128, NPIX / 64), blk, 0, stream>>>(
        xb, wqkv, qkv_b, qkv, NPIX, 3 * DIM, DIM);

    natten_mfma<<<dim3(100, 8), blk, 0, stream>>>(qkv, rpb, aout);

    // proj: M=6400, N=512. BM=64 x BN=64 -> grid 8 x 100 = 800 blocks.
    gemm_sb<64, 64, float><<<dim3(DIM / 64, NPIX / 64), blk, 0, stream>>>(
        aout, wproj, proj_b, out, NPIX, DIM, DIM);
}

// Round 12
// 121.904 us; speedup vs baseline: 1.3542x; 1.0387x over previous
//
#include <hip/hip_runtime.h>
#include <hip/hip_bf16.h>

// Nat2D neighborhood attention, MI355X gfx950.
// Device ABI: f32 in/out. bf16 MFMA everywhere (GEMMs + natten).
// Pipeline: [cast3 -> bf16] -> [gemm_db<64,128> QKV -> bf16 qkv] ->
//           [natten_mfma] -> [gemm_db<64,64> proj -> f32 out]
// gemm_db = double-buffered LDS, counted s_waitcnt vmcnt(N) (prefetch stays
// in flight across raw s_barriers -- T3/T4 minimal port) + XCD-chunked
// blockIdx swizzle (T1) for per-XCD L2 panel locality.

typedef __attribute__((ext_vector_type(4))) float f32x4;
typedef __attribute__((ext_vector_type(8))) short bf16x8;
typedef __attribute__((ext_vector_type(4))) short s16x4;

#define HEADS 8
#define HEAD_DIM 64
#define DIM 512
#define KW 7
#define HH 80
#define WW 80
#define NPIX (HH * WW)

__device__ inline unsigned short f2bf(float f) {
    union { __hip_bfloat16 b; unsigned short u; } cvt;
    cvt.b = __float2bfloat16(f);
    return cvt.u;
}
__device__ inline float bf2f(short s) {
    union { float f; unsigned u; } c;
    c.u = ((unsigned)(unsigned short)s) << 16;
    return c.f;
}

__device__ inline void storeC(float* p, float v) { *p = v; }
__device__ inline void storeC(__hip_bfloat16* p, float v) { *p = __float2bfloat16(v); }

// async global->LDS, 16B per lane. LDS dest must be linear in lane order.
__device__ inline void g2l16(const void* g, void* l) {
    __builtin_amdgcn_global_load_lds(
        (const __attribute__((address_space(1))) unsigned int*)g,
        (__attribute__((address_space(3))) unsigned int*)l,
        16, 0, 0);
}

// Fused f32 -> bf16 cast for three arrays (x, qkv_w, proj_w).
__global__ __launch_bounds__(256) void cast3_f32_bf16(
    const float* __restrict__ a, short* __restrict__ oa, int na4,
    const float* __restrict__ b, short* __restrict__ ob, int nb4,
    const float* __restrict__ c, short* __restrict__ oc, int nc4)
{
    int i = blockIdx.x * 256 + threadIdx.x;
    const float* src; short* dst; int idx;
    if (i < na4) { src = a; dst = oa; idx = i; }
    else if (i < na4 + nb4) { src = b; dst = ob; idx = i - na4; }
    else if (i < na4 + nb4 + nc4) { src = c; dst = oc; idx = i - na4 - nb4; }
    else return;
    f32x4 v = reinterpret_cast<const f32x4*>(src)[idx];
    s16x4 r;
#pragma unroll
    for (int j = 0; j < 4; ++j) r[j] = (short)f2bf(v[j]);
    reinterpret_cast<s16x4*>(dst)[idx] = r;
}

// C[m,n] = sum_k A[m,k] * W[n,k] + bias[n]   (A @ W^T + b)
// Double-buffered LDS, BK=64, 4 waves in 2x2 quadrants.
// Per K-step: stage(t+1 -> buf^1); s_waitcnt vmcnt(TASKS) [tile-t landed,
// tile-t+1 in flight]; s_barrier; MFMA(buf); s_barrier.  Raw barriers carry
// no vmcnt(0) drain -> prefetch survives (T3/T4). XOR-swizzle on SOURCE
// chunk + same XOR on ds_read (rule #21; LDS dest linear for g2l16).
// 1D grid with bijective XCD-chunked swizzle (requires gridDim.x % 8 == 0).
template <int BM, int BN, typename CT>
__global__ __launch_bounds__(256) void gemm_db(
    const __hip_bfloat16* __restrict__ A,
    const __hip_bfloat16* __restrict__ W,
    const float* __restrict__ bias,
    CT* __restrict__ C,
    int M, int N, int K, int gxn)
{
    constexpr int WM = BM / 2, WN = BN / 2;
    constexpr int MI = WM / 16, NI = WN / 16;
    constexpr int TASKS = (BM + BN) / 32;    // g2l16 per thread per K-tile
    __shared__ __align__(16) short lds[2][(BM + BN) * 64];

    // T1: XCD-chunked bijective swizzle (consecutive HW ids round-robin
    // XCDs; give each XCD a contiguous work chunk so its W/A panels stay L2-hot)
    const int cpx = gridDim.x >> 3;
    const int w = (blockIdx.x & 7) * cpx + (blockIdx.x >> 3);
    const int r0 = (w / gxn) * BM;
    const int c0 = (w % gxn) * BN;

    const int tid = threadIdx.x;
    const int lane = tid & 63;
    const int wv = tid >> 6;
    const int wr = wv >> 1;
    const int wc = wv & 1;
    const int rf = lane & 15;
    const int kg = lane >> 4;
    const int NT = K >> 6;

    // stage K-tile t into lds[buf]; slots 0..BM*8-1 = A rows, rest = W rows
    auto stage = [&](int t, int buf) {
#pragma unroll
        for (int q = 0; q < TASKS; ++q) {
            const int L = q * 256 + tid;          // 16B-slot index
            const int r = L >> 3;
            const int cs = (L & 7) ^ (r & 7);     // inverse-swizzled source chunk
            const __hip_bfloat16* src =
                (r < BM) ? A + (size_t)(r0 + r) * K + t * 64 + cs * 8
                         : W + (size_t)(c0 + (r - BM)) * K + t * 64 + cs * 8;
            g2l16(src, &lds[buf][(size_t)L * 8]);
        }
    };
    // read logical chunk ch (8 bf16) of linear slot-row `row` (A: 0..BM-1,
    // W: BM..BM+BN-1); swizzle key (row&7) matches stage (BM % 8 == 0).
    auto frag = [&](int buf, int row, int ch) -> bf16x8 {
        return *reinterpret_cast<const bf16x8*>(
            &lds[buf][row * 64 + ((ch ^ (row & 7)) << 3)]);
    };

    f32x4 acc[MI][NI] = {};

    stage(0, 0);
    for (int t = 0; t < NT; ++t) {
        const int buf = t & 1;
        if (t + 1 < NT) {
            stage(t + 1, buf ^ 1);
            asm volatile("s_waitcnt vmcnt(%0)" :: "n"(TASKS) : "memory");
        } else {
            asm volatile("s_waitcnt vmcnt(0)" ::: "memory");
        }
        __builtin_amdgcn_sched_barrier(0);
        __builtin_amdgcn_s_barrier();          // tile-t visible to all waves
        __builtin_amdgcn_sched_barrier(0);
#pragma unroll
        for (int ks = 0; ks < 2; ++ks) {
            bf16x8 af[MI], bfr[NI];
#pragma unroll
            for (int i = 0; i < MI; ++i)
                af[i] = frag(buf, wr * WM + i * 16 + rf, ks * 4 + kg);
#pragma unroll
            for (int j = 0; j < NI; ++j)
                bfr[j] = frag(buf, BM + wc * WN + j * 16 + rf, ks * 4 + kg);
#pragma unroll
            for (int i = 0; i < MI; ++i)
#pragma unroll
                for (int j = 0; j < NI; ++j)
                    acc[i][j] = __builtin_amdgcn_mfma_f32_16x16x32_bf16(af[i], bfr[j], acc[i][j], 0, 0, 0);
        }
        // all ds_reads are consumed by MFMAs above (lgkmcnt-drained by use);
        // barrier2 = pure execution sync before buf is re-staged next iter.
        __builtin_amdgcn_sched_barrier(0);
        __builtin_amdgcn_s_barrier();
    }

    // C/D layout: col = lane&15, row = (lane>>4)*4 + reg  [m89-verified]
#pragma unroll
    for (int j = 0; j < NI; ++j) {
        const int col = c0 + wc * WN + j * 16 + rf;
        const float bcol = bias[col];
#pragma unroll
        for (int i = 0; i < MI; ++i) {
#pragma unroll
            for (int r = 0; r < 4; ++r) {
                const int row = r0 + wr * WM + i * 16 + kg * 4 + r;
                storeC(C + (size_t)row * N + col, acc[i][j][r] + bcol);
            }
        }
    }
}

// natten_mfma: block = (8x8 pixel tile) x (one head), 256 threads = 4 waves.
// S = Q(64x64)·K^T(208x64) via MFMA; bias+mask+softmax per-row; P -> LDS;
// V^T -> LDS; O = P·V via MFMA + VALU tail. LDS time-shared, 52 KB.
__global__ __launch_bounds__(256, 3) void natten_mfma(
    const __hip_bfloat16* __restrict__ qkv,
    const float* __restrict__ rpb,
    __hip_bfloat16* __restrict__ aout)
{
    __shared__ __align__(16) short reg1[13312];  // sK [208][64] swz -> sP [64][208]
    __shared__ __align__(16) short reg2[13312];  // sQ [64][64] swz + sB -> sVT [64][208]
    short* sK  = reg1;
    short* sP  = reg1;
    short* sQ  = reg2;
    float* sB  = (float*)(reg2 + 4096);
    short* sVT = reg2;

    const int tid = threadIdx.x;
    const int lane = tid & 63;
    const int wv = tid >> 6;
    const int l15 = lane & 15;
    const int kg = lane >> 4;
    const int h = blockIdx.y;
    const int ti = blockIdx.x / 10;
    const int tj = blockIdx.x - ti * 10;
    const int R0 = ti * 8 - 3;
    const int C0 = tj * 8 - 3;

    if (tid < 169) sB[tid] = rpb[h * 169 + tid];

    // Stage Q (64 rows x 8 chunks), XOR-swizzled source
#pragma unroll
    for (int i = 0; i < 2; ++i) {
        const int L = i * 256 + tid;
        const int row = L >> 3, ch = L & 7;
        const int pi = ti * 8 + (row >> 3), pjg = tj * 8 + (row & 7);
        const int cs = ch ^ (row & 7);
        g2l16(qkv + ((size_t)(pi * WW + pjg) * 1536 + h * 64 + cs * 8),
              sQ + (size_t)L * 8);
    }
    // Stage K halo (196 slots x 8 chunks), swizzled
#pragma unroll
    for (int i = 0; i < 7; ++i) {
        const int t = i * 256 + tid;
        if (t < 1568) {
            const int slot = t >> 3, ch = t & 7;
            const int r = slot / 14, c = slot - r * 14;
            int gi = R0 + r; gi = gi < 0 ? 0 : (gi > 79 ? 79 : gi);
            int gj = C0 + c; gj = gj < 0 ? 0 : (gj > 79 ? 79 : gj);
            const int cs = ch ^ (slot & 7);
            g2l16(qkv + ((size_t)(gi * WW + gj) * 1536 + 512 + h * 64 + cs * 8),
                  sK + (size_t)t * 8);
        }
    }
    __syncthreads();   // bar1: Q,K,sB ready

    // Issue V loads to regs (consumed after bar2; hides under S)
    bf16x8 vbuf[7];
#pragma unroll
    for (int i = 0; i < 7; ++i) {
        const int t = i * 256 + tid;
        if (t < 1568) {
            const int slot = t % 196, ch = t / 196;
            const int r = slot / 14, c = slot - r * 14;
            int gi = R0 + r; gi = gi < 0 ? 0 : (gi > 79 ? 79 : gi);
            int gj = C0 + c; gj = gj < 0 ? 0 : (gj > 79 ? 79 : gj);
            vbuf[i] = *reinterpret_cast<const bf16x8*>(
                qkv + ((size_t)(gi * WW + gj) * 1536 + 1024 + h * 64 + ch * 8));
        }
    }

    auto fragswz = [&](const short* base, int row, int ch) -> bf16x8 {
        return *reinterpret_cast<const bf16x8*>(base + row * 64 + ((ch ^ (row & 7)) << 3));
    };

    // S = Q·K^T  (wave wv owns rows wv*16..+15)
    f32x4 acc[13];
#pragma unroll
    for (int nt = 0; nt < 13; ++nt) acc[nt] = f32x4{0.f, 0.f, 0.f, 0.f};
    {
        bf16x8 aq0 = fragswz(sQ, wv * 16 + l15, kg);
        bf16x8 aq1 = fragswz(sQ, wv * 16 + l15, 4 + kg);
#pragma unroll
        for (int nt = 0; nt < 13; ++nt) {
            bf16x8 bk0 = fragswz(sK, nt * 16 + l15, kg);
            bf16x8 bk1 = fragswz(sK, nt * 16 + l15, 4 + kg);
            acc[nt] = __builtin_amdgcn_mfma_f32_16x16x32_bf16(aq0, bk0, acc[nt], 0, 0, 0);
            acc[nt] = __builtin_amdgcn_mfma_f32_16x16x32_bf16(aq1, bk1, acc[nt], 0, 0, 0);
        }
    }

    // bias + mask + softmax (C/D: row = kg*4+reg, col = nt*16+l15)
    int pil[4], pjl[4], sil[4], sjl[4];
#pragma unroll
    for (int rg = 0; rg < 4; ++rg) {
        const int px = wv * 16 + kg * 4 + rg;
        const int pl = px >> 3, pw = px & 7;
        const int pi = ti * 8 + pl, pjg = tj * 8 + pw;
        int si = pi - 3; si = si < 0 ? 0 : (si > 73 ? 73 : si);
        int sj = pjg - 3; sj = sj < 0 ? 0 : (sj > 73 ? 73 : sj);
        pil[rg] = pl; pjl[rg] = pw;
        sil[rg] = si - R0; sjl[rg] = sj - C0;
    }
    float m4[4] = {-1e30f, -1e30f, -1e30f, -1e30f};
#pragma unroll
    for (int nt = 0; nt < 13; ++nt) {
        const int slot = nt * 16 + l15;
        const int r = slot / 14, c = slot - (slot / 14) * 14;
        const bool sv = slot < 196;
#pragma unroll
        for (int rg = 0; rg < 4; ++rg) {
            const unsigned a = (unsigned)(r - sil[rg]);
            const unsigned b = (unsigned)(c - sjl[rg]);
            float lv = -1e30f;
            if (sv && a < 7u && b < 7u)
                lv = 0.125f * acc[nt][rg] +
                     sB[(r - pil[rg] + 3) * 13 + (c - pjl[rg] + 3)];
            acc[nt][rg] = lv;
            m4[rg] = fmaxf(m4[rg], lv);
        }
    }
#pragma unroll
    for (int rg = 0; rg < 4; ++rg) {
        m4[rg] = fmaxf(m4[rg], __shfl_xor(m4[rg], 1, 64));
        m4[rg] = fmaxf(m4[rg], __shfl_xor(m4[rg], 2, 64));
        m4[rg] = fmaxf(m4[rg], __shfl_xor(m4[rg], 4, 64));
        m4[rg] = fmaxf(m4[rg], __shfl_xor(m4[rg], 8, 64));
    }
    float s4[4] = {0.f, 0.f, 0.f, 0.f};
#pragma unroll
    for (int nt = 0; nt < 13; ++nt)
#pragma unroll
        for (int rg = 0; rg < 4; ++rg) {
            const float e = __expf(acc[nt][rg] - m4[rg]);
            acc[nt][rg] = e;
            s4[rg] += e;
        }
#pragma unroll
    for (int rg = 0; rg < 4; ++rg) {
        s4[rg] += __shfl_xor(s4[rg], 1, 64);
        s4[rg] += __shfl_xor(s4[rg], 2, 64);
        s4[rg] += __shfl_xor(s4[rg], 4, 64);
        s4[rg] += __shfl_xor(s4[rg], 8, 64);
    }
    float rs[4];
#pragma unroll
    for (int rg = 0; rg < 4; ++rg) rs[rg] = 1.0f / s4[rg];

    __syncthreads();   // bar2: done reading sK/sQ/sB

    // Write P (bf16, un-normalized exp) to sP [64][208]
#pragma unroll
    for (int nt = 0; nt < 13; ++nt) {
        const int slot = nt * 16 + l15;
#pragma unroll
        for (int rg = 0; rg < 4; ++rg) {
            const int px = wv * 16 + kg * 4 + rg;
            sP[px * 208 + slot] = (short)f2bf(acc[nt][rg]);
        }
    }
    // Write V^T [d][slot] from vbuf; zero cols 196..207
#pragma unroll
    for (int i = 0; i < 7; ++i) {
        const int t = i * 256 + tid;
        if (t < 1568) {
            const int slot = t % 196, ch = t / 196;
#pragma unroll
            for (int j = 0; j < 8; ++j)
                sVT[(ch * 8 + j) * 208 + slot] = vbuf[i][j];
        }
    }
#pragma unroll
    for (int i = 0; i < 3; ++i) {
        const int idx = i * 256 + tid;
        if (idx < 768) sVT[(idx / 12) * 208 + 196 + (idx - (idx / 12) * 12)] = 0;
    }
    __syncthreads();   // bar3: P, V^T ready

    // O = P·V
    f32x4 oacc[4];
#pragma unroll
    for (int nt = 0; nt < 4; ++nt) oacc[nt] = f32x4{0.f, 0.f, 0.f, 0.f};
#pragma unroll
    for (int ks = 0; ks < 6; ++ks) {
        bf16x8 ap = *reinterpret_cast<const bf16x8*>(
            sP + (wv * 16 + l15) * 208 + (ks * 4 + kg) * 8);
#pragma unroll
        for (int nt = 0; nt < 4; ++nt) {
            bf16x8 bv = *reinterpret_cast<const bf16x8*>(
                sVT + (nt * 16 + l15) * 208 + (ks * 4 + kg) * 8);
            oacc[nt] = __builtin_amdgcn_mfma_f32_16x16x32_bf16(ap, bv, oacc[nt], 0, 0, 0);
        }
    }
    // VALU tail: slots 192..195
#pragma unroll
    for (int s = 192; s < 196; ++s) {
        float pw[4];
#pragma unroll
        for (int rg = 0; rg < 4; ++rg)
            pw[rg] = bf2f(sP[(wv * 16 + kg * 4 + rg) * 208 + s]);
#pragma unroll
        for (int nt = 0; nt < 4; ++nt) {
            const float vv = bf2f(sVT[(nt * 16 + l15) * 208 + s]);
#pragma unroll
            for (int rg = 0; rg < 4; ++rg)
                oacc[nt][rg] += pw[rg] * vv;
        }
    }

    // Epilogue
#pragma unroll
    for (int rg = 0; rg < 4; ++rg) {
        const int px = wv * 16 + kg * 4 + rg;
        const int pi = ti * 8 + (px >> 3), pjg = tj * 8 + (px & 7);
        __hip_bfloat16* dst = aout + (size_t)(pi * WW + pjg) * 512 + h * 64;
        const float rsv = rs[rg];
#pragma unroll
        for (int nt = 0; nt < 4; ++nt)
            dst[nt * 16 + l15] = __float2bfloat16(oacc[nt][rg] * rsv);
    }
}

extern "C" void kernel_launch(void* const* d_in, const int* in_sizes, int n_in,
                              void* d_out, int out_size, void* d_ws, size_t ws_size,
                              hipStream_t stream) {
    const float* x      = (const float*)d_in[0];
    const float* qkv_w  = (const float*)d_in[1];
    const float* qkv_b  = (const float*)d_in[2];
    const float* rpb    = (const float*)d_in[3];
    const float* proj_w = (const float*)d_in[4];
    const float* proj_b = (const float*)d_in[5];
    float* out = (float*)d_out;

    // ws layout (all bf16): xb | wqkv | wproj | qkv | aout  = 34.9 MB total
    char* wsb = (char*)d_ws;
    __hip_bfloat16* xb    = (__hip_bfloat16*)wsb;                 // 6,553,600 B
    __hip_bfloat16* wqkv  = (__hip_bfloat16*)(wsb + 6553600);     // 1,572,864 B
    __hip_bfloat16* wproj = (__hip_bfloat16*)(wsb + 8126464);     //   524,288 B
    __hip_bfloat16* qkv   = (__hip_bfloat16*)(wsb + 8650752);     // 19,660,800 B
    __hip_bfloat16* aout  = (__hip_bfloat16*)(wsb + 28311552);    // 6,553,600 B

    dim3 blk(256);
    cast3_f32_bf16<<<dim3((819200 + 196608 + 65536 + 255) / 256), blk, 0, stream>>>(
        x, (short*)xb, 819200, qkv_w, (short*)wqkv, 196608, proj_w, (short*)wproj, 65536);

    // QKV: M=6400, N=1536, K=512. 64x128 tiles -> 100*12 = 1200 blocks (%8==0).
    gemm_db<64, 128, __hip_bfloat16><<<dim3(1200), blk, 0, stream>>>(
        xb, wqkv, qkv_b, qkv, NPIX, 3 * DIM, DIM, 12);

    natten_mfma<<<dim3(100, 8), blk, 0, stream>>>(qkv, rpb, aout);

    // proj: M=6400, N=512. 64x64 tiles -> 100*8 = 800 blocks (%8==0).
    gemm_db<64, 64, float><<<dim3(800), blk, 0, stream>>>(
        aout, wproj, proj_b, out, NPIX, DIM, DIM, 8);
}